// Round 4
// baseline (470.157 us; speedup 1.0000x reference)
//
#include <hip/hip_runtime.h>

#define LOG2E 1.44269504088896340736f

typedef __attribute__((ext_vector_type(8))) _Float16 half8;
typedef __attribute__((ext_vector_type(4))) float floatx4;

// ---------------------------------------------------------------------------
// Prep (one 256-thread block, runs every launch — ws is re-poisoned):
//  - W1e[64][6]: fold W1's symmetric column pairs (s is symmetric, diag 0)
//  - W2h/W2l[64][64] f16: split-precision W2 (hi = f16(w), lo = f16(w-hi))
// ---------------------------------------------------------------------------
__global__ void prep_weights(const float* __restrict__ W1,
                             const float* __restrict__ W2,
                             float* __restrict__ W1e,
                             _Float16* __restrict__ W2h,
                             _Float16* __restrict__ W2l) {
    const int t = threadIdx.x;  // 256
    if (t < 64) {
        const int pa[6] = {0, 0, 0, 1, 1, 2};
        const int pb[6] = {1, 2, 3, 2, 3, 3};
#pragma unroll
        for (int p = 0; p < 6; ++p)
            W1e[t * 6 + p] = W1[t * 16 + pa[p] * 4 + pb[p]] + W1[t * 16 + pb[p] * 4 + pa[p]];
    }
#pragma unroll
    for (int e = t; e < 4096; e += 256) {
        const float f = W2[e];
        const _Float16 hi = (_Float16)f;
        W2h[e] = hi;
        W2l[e] = (_Float16)(f - (float)hi);
    }
}

// ---------------------------------------------------------------------------
// Fused kernel, barrier-free wave-local pipeline (round-2 structure).
// Wave w computes h for nodes [w*64, w*64+64) (its own lanes), stages h as
// f16 in its own LDS slice, then MFMAs those same rows — the LDS handoff is
// wave-local, so NO __syncthreads: just s_waitcnt lgkmcnt(0).
//
// Phase 2 uses OPERAND-SWAPPED MFMA: mfma(W2frag, hfrag) computes the
// transposed tile D[channel][node]; lane&15 -> the lane's own node,
// q*4+reg -> 4 consecutive channels -> one float4 store per (c,s); each
// store instruction covers 16 fully-written 64 B lines.
// (Plain stores: nontemporal measured -15 us regression in round 1.)
//
// SINGLE CHANGE vs round 2 (428.4 us): occupancy 4 -> 5 blocks/CU.
// B-fragments are loaded per-c from the precomputed f16 tables inside the
// c-loop (L1-hot, no conversion work), so the long-lived register set is
// just Ah[4][2] (32 VGPR) and peak live ~80 VGPR fits the (256,5) cap
// (~96-102) without spills. LDS 5 x 32 KB = 160 KB exactly.
// (Round-3 lesson: (256,5) with fat per-c f32 loads + cvt spilled and
// cost +39 us — occupancy bumps only work with a slim live set.)
// ---------------------------------------------------------------------------
__global__ __launch_bounds__(256, 5) void vnmlp_mfma(
    const float* __restrict__ node_pos,   // [N,3]
    const float* __restrict__ vn_pos,     // [G,12]
    const void*  __restrict__ batch_raw,  // [N] int32 or int64 (probed)
    const float* __restrict__ W1e,        // [64,6]
    const _Float16* __restrict__ W2h,     // [64,64] f16 hi
    const _Float16* __restrict__ W2l,     // [64,64] f16 lo
    const float* __restrict__ b1,         // [64]
    const float* __restrict__ b2,         // [64]
    float*       __restrict__ out,        // [N,64]
    int n)
{
    __shared__ _Float16 lds_h[256 * 64];  // 32 KB

    const int t    = threadIdx.x;
    const int base = blockIdx.x * 256;
    const int i    = base + t;
    const int ic   = (i < n) ? i : (n - 1);   // clamped: loads always safe
    const bool full = (base + 256 <= n);      // block-uniform

    const int l  = t & 63;
    const int w  = t >> 6;
    const int lm = l & 15;   // node index within 16-tile
    const int q  = l >> 4;   // quarter-wave

    // ---- Phase 1: per-node h (uniform, no divergence; ic-clamped) ----
    // batch dtype probe (int32 vs int64), wave-uniform
    const int* b32 = (const int*)batch_raw;
    const int probe = b32[(n / 2) | 1] | b32[(n / 4) | 1] | b32[((n / 4) * 3) | 1];
    long long bi;
    if (probe == 0) bi = ((const long long*)batch_raw)[ic];
    else            bi = (long long)b32[ic];

    const float px = node_pos[3 * ic + 0];
    const float py = node_pos[3 * ic + 1];
    const float pz = node_pos[3 * ic + 2];

    // vn_pos row: 48 B, 16 B-aligned (48*bi % 16 == 0) -> 3x float4
    const float4* vp4 = (const float4*)(vn_pos + 12 * bi);
    const float4 v0 = vp4[0], v1 = vp4[1], v2 = vp4[2];
    const float vx[4] = {px - v0.x, px - v0.w, px - v1.z, px - v2.y};
    const float vy[4] = {py - v0.y, py - v1.x, py - v1.w, py - v2.z};
    const float vz[4] = {pz - v0.z, pz - v1.y, pz - v2.x, pz - v2.w};

    float dn[6];
    float ss = 0.0f;
    {
        int p = 0;
#pragma unroll
        for (int a = 0; a < 4; ++a) {
#pragma unroll
            for (int k = a + 1; k < 4; ++k) {
                const float dx = vx[a] - vx[k];
                const float dy = vy[a] - vy[k];
                const float dz = vz[a] - vz[k];
                const float sq = dx * dx + dy * dy + dz * dz;
                dn[p++] = __builtin_amdgcn_sqrtf(sq);
                ss += sq;
            }
        }
    }
    ss *= 2.0f;  // each unique pair appears twice in the 16-vector
    const float inv = __builtin_amdgcn_rcpf(__builtin_amdgcn_sqrtf(ss) + 0.001f);
#pragma unroll
    for (int p = 0; p < 6; ++p) dn[p] *= inv;

    // h produced in chunks of 8 -> silu -> f16 -> LDS (low live-register).
    // LDS XOR-chunk swizzle: chunk c of node t at chunk index c ^ (t&7).
#pragma unroll
    for (int c = 0; c < 8; ++c) {
        half8 v;
#pragma unroll
        for (int jj = 0; jj < 8; ++jj) {
            const int j = c * 8 + jj;
            float acc = b1[j];
#pragma unroll
            for (int p = 0; p < 6; ++p)
                acc = fmaf(dn[p], W1e[j * 6 + p], acc);
            const float e = __builtin_amdgcn_exp2f(-LOG2E * acc);
            v[jj] = (_Float16)(acc * __builtin_amdgcn_rcpf(1.0f + e));
        }
        *(half8*)&lds_h[t * 64 + ((c ^ (t & 7)) * 8)] = v;
    }

    // Wave-local handoff: our MFMA rows were written by our own lanes.
    __asm__ volatile("s_waitcnt lgkmcnt(0)" ::: "memory");

    // ---- Phase 2: per-wave MFMA, wave w owns nodes [w*64, w*64+64) ----
    // Preload all A-fragments (this wave's own h rows): 8 ds_read_b128.
    half8 Ah[4][2];
#pragma unroll
    for (int s = 0; s < 4; ++s) {
        const int nn = w * 64 + s * 16 + lm;
#pragma unroll
        for (int ks = 0; ks < 2; ++ks) {
            const int kc = ks * 4 + q;
            Ah[s][ks] = *(const half8*)&lds_h[nn * 64 + ((kc ^ (nn & 7)) * 8)];
        }
    }

#pragma unroll 1
    for (int c = 0; c < 4; ++c) {
        // B-fragments for channel group c, from precomputed f16 tables
        // (8 KB each, L1-hot). frag elem j of ks: W2*[(c*16+lm)*64+ks*32+q*8+j]
        half8 Bh[2], Bl[2];
#pragma unroll
        for (int ks = 0; ks < 2; ++ks) {
            const int off = (c * 16 + lm) * 64 + ks * 32 + q * 8;
            Bh[ks] = *(const half8*)(W2h + off);
            Bl[ks] = *(const half8*)(W2l + off);
        }
        // swapped layout: lane holds channels c*16 + q*4 .. +3 (row dim)
        const floatx4 bv = *(const floatx4*)(b2 + c * 16 + q * 4);

#pragma unroll
        for (int s = 0; s < 4; ++s) {
            floatx4 acc = bv;
#pragma unroll
            for (int ks = 0; ks < 2; ++ks) {
                acc = __builtin_amdgcn_mfma_f32_16x16x32_f16(Bh[ks], Ah[s][ks], acc, 0, 0, 0);
                acc = __builtin_amdgcn_mfma_f32_16x16x32_f16(Bl[ks], Ah[s][ks], acc, 0, 0, 0);
            }
            const int node = base + w * 64 + s * 16 + lm;  // lane's output row
            if (full || node < n)
                *(floatx4*)(out + (size_t)node * 64 + c * 16 + q * 4) = acc;
        }
    }
}

// ---------------------------------------------------------------------------
// Fallback (no workspace): LDS-coalesced stores, VALU matvec2.
// ---------------------------------------------------------------------------
__global__ __launch_bounds__(256) void vnmlp_fallback(
    const float* __restrict__ node_pos, const float* __restrict__ vn_pos,
    const void* __restrict__ batch_raw, const float* __restrict__ W1,
    const float* __restrict__ b1, const float* __restrict__ W2,
    const float* __restrict__ b2, float* __restrict__ out, int n)
{
    __shared__ float lds[256 * 36];
    const int t = threadIdx.x;
    const int base = blockIdx.x * 256;
    const int i = base + t;
    const bool valid = (i < n);

    float h[64];
    if (valid) {
        const int* b32 = (const int*)batch_raw;
        const int probe = b32[(n / 2) | 1] | b32[(n / 4) | 1] | b32[((n / 4) * 3) | 1];
        long long bi;
        if (probe == 0) bi = ((const long long*)batch_raw)[i];
        else            bi = (long long)b32[i];
        const float px = node_pos[3 * i], py = node_pos[3 * i + 1], pz = node_pos[3 * i + 2];
        const float* vp = vn_pos + 12 * bi;
        float vx[4], vy[4], vz[4];
#pragma unroll
        for (int k = 0; k < 4; ++k) {
            vx[k] = px - vp[3 * k]; vy[k] = py - vp[3 * k + 1]; vz[k] = pz - vp[3 * k + 2];
        }
        float dn[6]; float ss = 0.0f; int p = 0;
#pragma unroll
        for (int a = 0; a < 4; ++a)
#pragma unroll
            for (int k = a + 1; k < 4; ++k) {
                const float dx = vx[a] - vx[k], dy = vy[a] - vy[k], dz = vz[a] - vz[k];
                const float sq = dx * dx + dy * dy + dz * dz;
                dn[p++] = __builtin_amdgcn_sqrtf(sq); ss += sq;
            }
        ss *= 2.0f;
        const float inv = __builtin_amdgcn_rcpf(__builtin_amdgcn_sqrtf(ss) + 0.001f);
#pragma unroll
        for (int qq = 0; qq < 6; ++qq) dn[qq] *= inv;
        const int pa[6] = {0, 0, 0, 1, 1, 2}, pb[6] = {1, 2, 3, 2, 3, 3};
#pragma unroll
        for (int j = 0; j < 64; ++j) {
            float acc = b1[j];
#pragma unroll
            for (int qq = 0; qq < 6; ++qq)
                acc = fmaf(dn[qq], W1[j * 16 + pa[qq] * 4 + pb[qq]] + W1[j * 16 + pb[qq] * 4 + pa[qq]], acc);
            const float e = __builtin_amdgcn_exp2f(-LOG2E * acc);
            h[j] = acc * __builtin_amdgcn_rcpf(1.0f + e);
        }
    }
    float4* o4 = (float4*)out;
#pragma unroll 1
    for (int half = 0; half < 2; ++half) {
        if (half) __syncthreads();
        if (valid) {
#pragma unroll 1
            for (int j4 = 0; j4 < 8; ++j4) {
                const int j0 = half * 32 + j4 * 4;
                float a0 = b2[j0], a1 = b2[j0 + 1], a2 = b2[j0 + 2], a3 = b2[j0 + 3];
#pragma unroll
                for (int k = 0; k < 64; ++k) {
                    const float hk = h[k];
                    a0 = fmaf(hk, W2[(j0 + 0) * 64 + k], a0);
                    a1 = fmaf(hk, W2[(j0 + 1) * 64 + k], a1);
                    a2 = fmaf(hk, W2[(j0 + 2) * 64 + k], a2);
                    a3 = fmaf(hk, W2[(j0 + 3) * 64 + k], a3);
                }
                *(float4*)&lds[t * 36 + j4 * 4] = make_float4(a0, a1, a2, a3);
            }
        }
        __syncthreads();
#pragma unroll
        for (int r = 0; r < 8; ++r) {
            const int g = r * 256 + t, node = g >> 3, sub = g & 7;
            if (base + node < n)
                o4[(size_t)(base + node) * 16 + half * 8 + sub] = *(const float4*)&lds[node * 36 + sub * 4];
        }
    }
}

extern "C" void kernel_launch(void* const* d_in, const int* in_sizes, int n_in,
                              void* d_out, int out_size, void* d_ws, size_t ws_size,
                              hipStream_t stream) {
    // setup_inputs order: node_feat(0, unused), node_pos(1), vn_pos(2),
    // batch(3), W1(4), b1(5), W2(6), b2(7)
    const float* node_pos = (const float*)d_in[1];
    const float* vn_pos   = (const float*)d_in[2];
    const void*  batch    = d_in[3];
    const float* W1       = (const float*)d_in[4];
    const float* b1       = (const float*)d_in[5];
    const float* W2       = (const float*)d_in[6];
    const float* b2       = (const float*)d_in[7];
    float* out = (float*)d_out;

    const int n = in_sizes[1] / 3;
    const int blocks = (n + 255) / 256;

    // ws layout: W1e (1536 B) | W2h (8192 B) | W2l (8192 B)
    const size_t WS_NEED = 1536 + 8192 + 8192;
    if (ws_size >= WS_NEED) {
        float*    W1e = (float*)d_ws;
        _Float16* W2h = (_Float16*)((char*)d_ws + 1536);
        _Float16* W2l = (_Float16*)((char*)d_ws + 1536 + 8192);
        hipLaunchKernelGGL(prep_weights, dim3(1), dim3(256), 0, stream, W1, W2, W1e, W2h, W2l);
        hipLaunchKernelGGL(vnmlp_mfma, dim3(blocks), dim3(256), 0, stream,
                           node_pos, vn_pos, batch, W1e, W2h, W2l, b1, b2, out, n);
    } else {
        hipLaunchKernelGGL(vnmlp_fallback, dim3(blocks), dim3(256), 0, stream,
                           node_pos, vn_pos, batch, W1, b1, W2, b2, out, n);
    }
}

// Round 5
// 412.841 us; speedup vs baseline: 1.1388x; 1.1388x over previous
//
#include <hip/hip_runtime.h>

#define LOG2E 1.44269504088896340736f

typedef __attribute__((ext_vector_type(8))) _Float16 half8;
typedef __attribute__((ext_vector_type(4))) float floatx4;

// ---------------------------------------------------------------------------
// Prep (one 256-thread block, runs every launch — ws is re-poisoned):
//  - W1e[64][6]: fold W1's symmetric column pairs (s is symmetric, diag 0)
//  - W2h/W2l[64][64] f16: split-precision W2 (hi = f16(w), lo = f16(w-hi))
// ---------------------------------------------------------------------------
__global__ void prep_weights(const float* __restrict__ W1,
                             const float* __restrict__ W2,
                             float* __restrict__ W1e,
                             _Float16* __restrict__ W2h,
                             _Float16* __restrict__ W2l) {
    const int t = threadIdx.x;  // 256
    if (t < 64) {
        const int pa[6] = {0, 0, 0, 1, 1, 2};
        const int pb[6] = {1, 2, 3, 2, 3, 3};
#pragma unroll
        for (int p = 0; p < 6; ++p)
            W1e[t * 6 + p] = W1[t * 16 + pa[p] * 4 + pb[p]] + W1[t * 16 + pb[p] * 4 + pa[p]];
    }
#pragma unroll
    for (int e = t; e < 4096; e += 256) {
        const float f = W2[e];
        const _Float16 hi = (_Float16)f;
        W2h[e] = hi;
        W2l[e] = (_Float16)(f - (float)hi);
    }
}

// ---------------------------------------------------------------------------
// Fused kernel — round-2 structure ((256,4), B-frags prefetched, s-outer)
// with ONE change: LDS-staged LINEAR store epilogue.
//
// Round-2 direct stores: each instruction wrote 16 rows x 64 B at 256 B
// stride (line c of 16 rows) — 64 B-fragmented bursts; effective write BW
// ~2.4 TB/s vs the fill kernel's 6.4 TB/s (lane-consecutive bursts).
// New epilogue: per s-group (16 rows), the 4 acc float4s are ds_written
// (XOR-swizzled) into the wave's own now-dead h slice, read back linearly,
// and stored as 4 x 1 KB lane-consecutive contiguous bursts (fill-identical
// pattern; 4 KB contiguous per s-group). Wave-local only — barrier-free
// pipeline preserved (LDS ops are in-order per wave).
//
// History: nt stores -15 us (r1); launch_bounds(256,5) -40 us (r3/r4);
// swapped-operand MFMA epilogue +6 us win (r2).
// ---------------------------------------------------------------------------
__global__ __launch_bounds__(256, 4) void vnmlp_mfma(
    const float* __restrict__ node_pos,   // [N,3]
    const float* __restrict__ vn_pos,     // [G,12]
    const void*  __restrict__ batch_raw,  // [N] int32 or int64 (probed)
    const float* __restrict__ W1e,        // [64,6]
    const _Float16* __restrict__ W2h,     // [64,64] f16 hi
    const _Float16* __restrict__ W2l,     // [64,64] f16 lo
    const float* __restrict__ b1,         // [64]
    const float* __restrict__ b2,         // [64]
    float*       __restrict__ out,        // [N,64]
    int n)
{
    __shared__ _Float16 lds_h[256 * 64];  // 32 KB; 8 KB slice per wave

    const int t    = threadIdx.x;
    const int base = blockIdx.x * 256;
    const int i    = base + t;
    const int ic   = (i < n) ? i : (n - 1);   // clamped: loads always safe
    const bool full = (base + 256 <= n);      // block-uniform

    const int l  = t & 63;
    const int w  = t >> 6;
    const int lm = l & 15;   // node index within 16-tile
    const int q  = l >> 4;   // quarter-wave

    // ---- prefetch W2 fragments + bias early (16 KB tables, L1-hot) ----
    half8 Bh[4][2], Bl[4][2];
    floatx4 bv4[4];
#pragma unroll
    for (int c = 0; c < 4; ++c) {
#pragma unroll
        for (int ks = 0; ks < 2; ++ks) {
            const int off = (c * 16 + lm) * 64 + ks * 32 + q * 8;
            Bh[c][ks] = *(const half8*)(W2h + off);
            Bl[c][ks] = *(const half8*)(W2l + off);
        }
        // swapped layout: lane holds channels c*16 + q*4 .. +3 (row dim)
        bv4[c] = *(const floatx4*)(b2 + c * 16 + q * 4);
    }

    // ---- Phase 1: per-node h (uniform, no divergence; ic-clamped) ----
    const int* b32 = (const int*)batch_raw;
    const int probe = b32[(n / 2) | 1] | b32[(n / 4) | 1] | b32[((n / 4) * 3) | 1];
    long long bi;
    if (probe == 0) bi = ((const long long*)batch_raw)[ic];
    else            bi = (long long)b32[ic];

    const float px = node_pos[3 * ic + 0];
    const float py = node_pos[3 * ic + 1];
    const float pz = node_pos[3 * ic + 2];

    // vn_pos row: 48 B, 16 B-aligned (48*bi % 16 == 0) -> 3x float4
    const float4* vp4 = (const float4*)(vn_pos + 12 * bi);
    const float4 v0 = vp4[0], v1 = vp4[1], v2 = vp4[2];
    const float vx[4] = {px - v0.x, px - v0.w, px - v1.z, px - v2.y};
    const float vy[4] = {py - v0.y, py - v1.x, py - v1.w, py - v2.z};
    const float vz[4] = {pz - v0.z, pz - v1.y, pz - v2.x, pz - v2.w};

    float dn[6];
    float ss = 0.0f;
    {
        int p = 0;
#pragma unroll
        for (int a = 0; a < 4; ++a) {
#pragma unroll
            for (int k = a + 1; k < 4; ++k) {
                const float dx = vx[a] - vx[k];
                const float dy = vy[a] - vy[k];
                const float dz = vz[a] - vz[k];
                const float sq = dx * dx + dy * dy + dz * dz;
                dn[p++] = __builtin_amdgcn_sqrtf(sq);
                ss += sq;
            }
        }
    }
    ss *= 2.0f;  // each unique pair appears twice in the 16-vector
    const float inv = __builtin_amdgcn_rcpf(__builtin_amdgcn_sqrtf(ss) + 0.001f);
#pragma unroll
    for (int p = 0; p < 6; ++p) dn[p] *= inv;

    // h produced in chunks of 8 -> silu -> f16 -> LDS (low live-register).
    // LDS XOR-chunk swizzle: chunk c of node t at chunk index c ^ (t&7).
#pragma unroll
    for (int c = 0; c < 8; ++c) {
        half8 v;
#pragma unroll
        for (int jj = 0; jj < 8; ++jj) {
            const int j = c * 8 + jj;
            float acc = b1[j];
#pragma unroll
            for (int p = 0; p < 6; ++p)
                acc = fmaf(dn[p], W1e[j * 6 + p], acc);
            const float e = __builtin_amdgcn_exp2f(-LOG2E * acc);
            v[jj] = (_Float16)(acc * __builtin_amdgcn_rcpf(1.0f + e));
        }
        *(half8*)&lds_h[t * 64 + ((c ^ (t & 7)) * 8)] = v;
    }

    // Wave-local handoff: our MFMA rows were written by our own lanes.
    __asm__ volatile("s_waitcnt lgkmcnt(0)" ::: "memory");

    // ---- Phase 2: per-wave MFMA + LDS-staged linear stores ----
    // Wave w's LDS slice (bytes w*8192..+8191) holds its own h rows:
    // node-local row r at byte offset r*128. Staging region = bytes 0..4095
    // of the slice — the h rows for s=0,1, which are DEAD once their
    // A-fragments are loaded (loaded pairwise below, before first staging).
    char* wbytes = (char*)lds_h + w * 8192;

#pragma unroll 1
    for (int sp = 0; sp < 2; ++sp) {
        // Load A-fragments for s = 2*sp, 2*sp+1 BEFORE staging overwrites
        // the region (sp=0 stages over s=0,1's h; sp=1's h is at 4096+).
        half8 Ah[2][2];
#pragma unroll
        for (int ss = 0; ss < 2; ++ss) {
            const int nn = w * 64 + (sp * 2 + ss) * 16 + lm;
#pragma unroll
            for (int ks = 0; ks < 2; ++ks) {
                const int kc = ks * 4 + q;
                Ah[ss][ks] = *(const half8*)&lds_h[nn * 64 + ((kc ^ (nn & 7)) * 8)];
            }
        }

#pragma unroll
        for (int ss = 0; ss < 2; ++ss) {
            const int s = sp * 2 + ss;
            // compute 4 channel-groups, stage each into LDS (swizzled)
#pragma unroll
            for (int c = 0; c < 4; ++c) {
                floatx4 acc = bv4[c];
#pragma unroll
                for (int ks = 0; ks < 2; ++ks) {
                    acc = __builtin_amdgcn_mfma_f32_16x16x32_f16(Bh[c][ks], Ah[ss][ks], acc, 0, 0, 0);
                    acc = __builtin_amdgcn_mfma_f32_16x16x32_f16(Bl[c][ks], Ah[ss][ks], acc, 0, 0, 0);
                }
                // stage: local row lm (0..15), byte = lm*256 + c*64 + q*16,
                // XOR-swizzled for uniform bank coverage
                const int sb = (lm * 256 + c * 64 + q * 16) ^ ((lm & 7) << 4);
                *(floatx4*)(wbytes + sb) = acc;
            }
            // linear drain: 4 KB contiguous (16 rows), 4 x 1 KB
            // lane-consecutive bursts. LDS in-order per wave: these reads
            // see the writes above; compiler inserts lgkm before store use.
            const int row0 = base + w * 64 + s * 16;       // first node
            float* oreg = out + (size_t)row0 * 64;
#pragma unroll
            for (int r = 0; r < 4; ++r) {
                const int g = r * 64 + l;                  // 16 B chunk idx
                const int row_l = g >> 4;                  // 0..15
                const int rb = (g * 16) ^ ((row_l & 7) << 4);
                const floatx4 v = *(const floatx4*)(wbytes + rb);
                if (full || (row0 + row_l) < n)
                    *(floatx4*)(oreg + g * 4) = v;
            }
        }
    }
}

// ---------------------------------------------------------------------------
// Fallback (no workspace): LDS-coalesced stores, VALU matvec2.
// ---------------------------------------------------------------------------
__global__ __launch_bounds__(256) void vnmlp_fallback(
    const float* __restrict__ node_pos, const float* __restrict__ vn_pos,
    const void* __restrict__ batch_raw, const float* __restrict__ W1,
    const float* __restrict__ b1, const float* __restrict__ W2,
    const float* __restrict__ b2, float* __restrict__ out, int n)
{
    __shared__ float lds[256 * 36];
    const int t = threadIdx.x;
    const int base = blockIdx.x * 256;
    const int i = base + t;
    const bool valid = (i < n);

    float h[64];
    if (valid) {
        const int* b32 = (const int*)batch_raw;
        const int probe = b32[(n / 2) | 1] | b32[(n / 4) | 1] | b32[((n / 4) * 3) | 1];
        long long bi;
        if (probe == 0) bi = ((const long long*)batch_raw)[i];
        else            bi = (long long)b32[i];
        const float px = node_pos[3 * i], py = node_pos[3 * i + 1], pz = node_pos[3 * i + 2];
        const float* vp = vn_pos + 12 * bi;
        float vx[4], vy[4], vz[4];
#pragma unroll
        for (int k = 0; k < 4; ++k) {
            vx[k] = px - vp[3 * k]; vy[k] = py - vp[3 * k + 1]; vz[k] = pz - vp[3 * k + 2];
        }
        float dn[6]; float ss = 0.0f; int p = 0;
#pragma unroll
        for (int a = 0; a < 4; ++a)
#pragma unroll
            for (int k = a + 1; k < 4; ++k) {
                const float dx = vx[a] - vx[k], dy = vy[a] - vy[k], dz = vz[a] - vz[k];
                const float sq = dx * dx + dy * dy + dz * dz;
                dn[p++] = __builtin_amdgcn_sqrtf(sq); ss += sq;
            }
        ss *= 2.0f;
        const float inv = __builtin_amdgcn_rcpf(__builtin_amdgcn_sqrtf(ss) + 0.001f);
#pragma unroll
        for (int qq = 0; qq < 6; ++qq) dn[qq] *= inv;
        const int pa[6] = {0, 0, 0, 1, 1, 2}, pb[6] = {1, 2, 3, 2, 3, 3};
#pragma unroll
        for (int j = 0; j < 64; ++j) {
            float acc = b1[j];
#pragma unroll
            for (int qq = 0; qq < 6; ++qq)
                acc = fmaf(dn[qq], W1[j * 16 + pa[qq] * 4 + pb[qq]] + W1[j * 16 + pb[qq] * 4 + pa[qq]], acc);
            const float e = __builtin_amdgcn_exp2f(-LOG2E * acc);
            h[j] = acc * __builtin_amdgcn_rcpf(1.0f + e);
        }
    }
    float4* o4 = (float4*)out;
#pragma unroll 1
    for (int half = 0; half < 2; ++half) {
        if (half) __syncthreads();
        if (valid) {
#pragma unroll 1
            for (int j4 = 0; j4 < 8; ++j4) {
                const int j0 = half * 32 + j4 * 4;
                float a0 = b2[j0], a1 = b2[j0 + 1], a2 = b2[j0 + 2], a3 = b2[j0 + 3];
#pragma unroll
                for (int k = 0; k < 64; ++k) {
                    const float hk = h[k];
                    a0 = fmaf(hk, W2[(j0 + 0) * 64 + k], a0);
                    a1 = fmaf(hk, W2[(j0 + 1) * 64 + k], a1);
                    a2 = fmaf(hk, W2[(j0 + 2) * 64 + k], a2);
                    a3 = fmaf(hk, W2[(j0 + 3) * 64 + k], a3);
                }
                *(float4*)&lds[t * 36 + j4 * 4] = make_float4(a0, a1, a2, a3);
            }
        }
        __syncthreads();
#pragma unroll
        for (int r = 0; r < 8; ++r) {
            const int g = r * 256 + t, node = g >> 3, sub = g & 7;
            if (base + node < n)
                o4[(size_t)(base + node) * 16 + half * 8 + sub] = *(const float4*)&lds[node * 36 + sub * 4];
        }
    }
}

extern "C" void kernel_launch(void* const* d_in, const int* in_sizes, int n_in,
                              void* d_out, int out_size, void* d_ws, size_t ws_size,
                              hipStream_t stream) {
    // setup_inputs order: node_feat(0, unused), node_pos(1), vn_pos(2),
    // batch(3), W1(4), b1(5), W2(6), b2(7)
    const float* node_pos = (const float*)d_in[1];
    const float* vn_pos   = (const float*)d_in[2];
    const void*  batch    = d_in[3];
    const float* W1       = (const float*)d_in[4];
    const float* b1       = (const float*)d_in[5];
    const float* W2       = (const float*)d_in[6];
    const float* b2       = (const float*)d_in[7];
    float* out = (float*)d_out;

    const int n = in_sizes[1] / 3;
    const int blocks = (n + 255) / 256;

    // ws layout: W1e (1536 B) | W2h (8192 B) | W2l (8192 B)
    const size_t WS_NEED = 1536 + 8192 + 8192;
    if (ws_size >= WS_NEED) {
        float*    W1e = (float*)d_ws;
        _Float16* W2h = (_Float16*)((char*)d_ws + 1536);
        _Float16* W2l = (_Float16*)((char*)d_ws + 1536 + 8192);
        hipLaunchKernelGGL(prep_weights, dim3(1), dim3(256), 0, stream, W1, W2, W1e, W2h, W2l);
        hipLaunchKernelGGL(vnmlp_mfma, dim3(blocks), dim3(256), 0, stream,
                           node_pos, vn_pos, batch, W1e, W2h, W2l, b1, b2, out, n);
    } else {
        hipLaunchKernelGGL(vnmlp_fallback, dim3(blocks), dim3(256), 0, stream,
                           node_pos, vn_pos, batch, W1, b1, W2, b2, out, n);
    }
}